// Round 3
// baseline (168.746 us; speedup 1.0000x reference)
//
#include <hip/hip_runtime.h>
#include <hip/hip_bf16.h>
#include <math.h>

#define B_     8192
#define LATENT 32
#define CIN    128
#define HID    256
#define ACTD   16
#define NE     8
#define GH     128
#define IN0    160   // LATENT + CIN
#define INTER  288   // HID + LATENT

typedef __attribute__((ext_vector_type(8))) short short8;
typedef __attribute__((ext_vector_type(4))) float f32x4;

__device__ __forceinline__ float elu1(float x) { return x > 0.0f ? x : expm1f(x); }

__device__ __forceinline__ unsigned short bfh(float v) {
    __hip_bfloat16 b = __float2bfloat16(v);
    return *reinterpret_cast<unsigned short*>(&b);
}
__device__ __forceinline__ float bf2f(unsigned short u) {
    __hip_bfloat16 b;
    *reinterpret_cast<unsigned short*>(&b) = u;
    return __bfloat162float(b);
}
__device__ __forceinline__ void gload16(const unsigned short* g, unsigned short* lds) {
    __builtin_amdgcn_global_load_lds((const __attribute__((address_space(1))) void*)g,
                                     (__attribute__((address_space(3))) void*)lds, 16, 0, 0);
}

// ---------- prep: transpose + hi/lo split all weight matrices ----------
__global__ __launch_bounds__(256) void k_prep(
    const float* __restrict__ w0, const float* __restrict__ w1, const float* __restrict__ w2,
    const float* __restrict__ g0w, const float* __restrict__ g1w,
    unsigned short* __restrict__ T0h, unsigned short* __restrict__ T0l,
    unsigned short* __restrict__ T1h, unsigned short* __restrict__ T1l,
    unsigned short* __restrict__ T2h, unsigned short* __restrict__ T2l,
    unsigned short* __restrict__ G0h, unsigned short* __restrict__ G0l,
    unsigned short* __restrict__ G1h, unsigned short* __restrict__ G1l)
{
    int id = blockIdx.x * 256 + threadIdx.x;
    float v; size_t dst; unsigned short *H, *L;
    if (id < 327680) {
        int o = id & 255, ei = id >> 8, i = ei % 160, e = ei / 160;
        v = w0[id]; H = T0h; L = T0l; dst = (size_t)(e * 256 + o) * 160 + i;
    } else if (id < 917504) {
        int t = id - 327680;
        int o = t & 255, ei = t >> 8, i = ei % 288, e = ei / 288;
        v = w1[t]; H = T1h; L = T1l; dst = (size_t)(e * 256 + o) * 288 + i;
    } else if (id < 954368) {
        int t = id - 917504;
        int o = t & 15, ei = t >> 4, i = ei % 288, e = ei / 288;
        v = w2[t]; H = T2h; L = T2l; dst = (size_t)(e * 16 + o) * 288 + i;
    } else if (id < 974848) {
        int t = id - 954368;
        int o = t & 127, i = t >> 7;
        v = g0w[t]; H = G0h; L = G0l; dst = (size_t)o * 160 + i;
    } else if (id < 991232) {
        int t = id - 974848;
        int o = t & 127, i = t >> 7;
        v = g1w[t]; H = G1h; L = G1l; dst = (size_t)o * 128 + i;
    } else return;
    unsigned short h = bfh(v);
    unsigned short lo = bfh(v - bf2f(h));
    H[dst] = h; L[dst] = lo;
}

// ---------- LayerNorm + concat, split to hi/lo; also seed z into X1/X2 ----------
__global__ __launch_bounds__(256) void k_ln_concat2(
    const float* __restrict__ z, const float* __restrict__ c,
    const float* __restrict__ g, const float* __restrict__ bt,
    unsigned short* __restrict__ X0h, unsigned short* __restrict__ X0l,
    unsigned short* __restrict__ X1h, unsigned short* __restrict__ X1l,
    unsigned short* __restrict__ X2h, unsigned short* __restrict__ X2l)
{
    int gid = blockIdx.x * 256 + threadIdx.x;
    int row = gid >> 6;
    int l = threadIdx.x & 63;
    if (row >= B_) return;
    const float* cr = c + (size_t)row * CIN;
    float v0 = cr[l], v1 = cr[l + 64];
    float s = v0 + v1;
    #pragma unroll
    for (int o = 32; o; o >>= 1) s += __shfl_xor(s, o);
    float mean = s * (1.0f / 128.0f);
    float d0 = v0 - mean, d1 = v1 - mean;
    float q = d0 * d0 + d1 * d1;
    #pragma unroll
    for (int o = 32; o; o >>= 1) q += __shfl_xor(q, o);
    float rstd = rsqrtf(q * (1.0f / 128.0f) + 1e-5f);
    float y0 = d0 * rstd * g[l] + bt[l];
    float y1 = d1 * rstd * g[l + 64] + bt[l + 64];
    size_t r0 = (size_t)row * IN0;
    unsigned short h0 = bfh(y0), lo0 = bfh(y0 - bf2f(h0));
    unsigned short h1 = bfh(y1), lo1 = bfh(y1 - bf2f(h1));
    X0h[r0 + 32 + l] = h0; X0l[r0 + 32 + l] = lo0;
    X0h[r0 + 96 + l] = h1; X0l[r0 + 96 + l] = lo1;
    if (l < LATENT) {
        float zv = z[(size_t)row * LATENT + l];
        unsigned short zh = bfh(zv), zl = bfh(zv - bf2f(zh));
        X0h[r0 + l] = zh; X0l[r0 + l] = zl;
        size_t r1 = (size_t)row * INTER;
        X1h[r1 + l] = zh; X1l[r1 + l] = zl;
        X2h[r1 + l] = zh; X2l[r1 + l] = zl;
    }
}

// ---------- generic hi/lo-split bf16 MFMA GEMM (NE_T=1 path: gates + final) ----------
template<int I_, int N_, int NE_T, int OUTM, int SOUT, int OFS>
__global__ __launch_bounds__(256) void k_mfma_gemm(
    const unsigned short* __restrict__ Ah, const unsigned short* __restrict__ Al,
    const unsigned short* __restrict__ Bh, const unsigned short* __restrict__ Bl,
    const float* __restrict__ bias, const float* __restrict__ coeff,
    float* __restrict__ outF, unsigned short* __restrict__ outH,
    unsigned short* __restrict__ outL)
{
    constexpr int KS = I_ / 32;
    __shared__ unsigned short smem[2][12288];
    __shared__ float bias_s[8][64];

    const int tid = threadIdx.x, wid = tid >> 6, l = tid & 63;
    const int wm = wid >> 1, wn = wid & 1;
    const int brow = blockIdx.y * 128, bn = blockIdx.x * 64;

    for (int idx = tid; idx < NE_T * 64; idx += 256)
        bias_s[idx >> 6][idx & 63] = bias[(idx >> 6) * N_ + bn + (idx & 63)];

    const int a_off  = (l >> 2) * I_ + (((l & 3) ^ ((l >> 3) & 3)) << 3);
    const int rd_off = ((l & 15) << 5) + (((l >> 4) ^ ((l >> 1) & 3)) << 3);

    const unsigned short* Abh = Ah + (size_t)brow * I_;
    const unsigned short* Abl = Al + (size_t)brow * I_;

    int se = 0, sk = 0, cur = 0;
    auto stage = [&](int bi) {
        unsigned short* buf = smem[bi];
        const int k0 = sk * 32;
        const unsigned short* ah = Abh + k0 + a_off;
        const unsigned short* al = Abl + k0 + a_off;
        const size_t bofs = (size_t)(se * N_ + bn) * I_ + k0 + a_off;
        const unsigned short* bh = Bh + bofs;
        const unsigned short* bl = Bl + bofs;
        gload16(ah + wid * 16 * I_,       buf + wid * 512);
        gload16(ah + (wid + 4) * 16 * I_, buf + (wid + 4) * 512);
        gload16(al + wid * 16 * I_,       buf + 4096 + wid * 512);
        gload16(al + (wid + 4) * 16 * I_, buf + 4096 + (wid + 4) * 512);
        gload16(bh + wid * 16 * I_,       buf + 8192 + wid * 512);
        gload16(bl + wid * 16 * I_,       buf + 10240 + wid * 512);
        if (++sk == KS) { sk = 0; ++se; }
    };

    f32x4 accW[4][2];

    stage(0);
    __syncthreads();

    {
        #pragma unroll
        for (int nf = 0; nf < 2; ++nf) {
            float bv = bias_s[0][wn * 32 + nf * 16 + (l & 15)];
            f32x4 bv4 = {bv, bv, bv, bv};
            #pragma unroll
            for (int mf = 0; mf < 4; ++mf) accW[mf][nf] = bv4;
        }
        for (int ks = 0; ks < KS; ++ks) {
            if (se < NE_T) {
                stage(cur ^ 1);
                asm volatile("s_waitcnt vmcnt(6)" ::: "memory");
            } else {
                asm volatile("s_waitcnt vmcnt(0)" ::: "memory");
            }
            __builtin_amdgcn_s_barrier();
            asm volatile("" ::: "memory");
            const unsigned short* bp = smem[cur];
            short8 afh[4], afl[4], bqh[2], bql[2];
            #pragma unroll
            for (int mf = 0; mf < 4; ++mf) {
                const int ro = (wm * 64 + mf * 16) * 32;
                afh[mf] = *(const short8*)(bp + ro + rd_off);
                afl[mf] = *(const short8*)(bp + 4096 + ro + rd_off);
            }
            #pragma unroll
            for (int nf = 0; nf < 2; ++nf) {
                const int ro = (wn * 32 + nf * 16) * 32;
                bqh[nf] = *(const short8*)(bp + 8192 + ro + rd_off);
                bql[nf] = *(const short8*)(bp + 10240 + ro + rd_off);
            }
            #pragma unroll
            for (int mf = 0; mf < 4; ++mf)
                #pragma unroll
                for (int nf = 0; nf < 2; ++nf) {
                    accW[mf][nf] = __builtin_amdgcn_mfma_f32_16x16x32_bf16(afh[mf], bqh[nf], accW[mf][nf], 0, 0, 0);
                    accW[mf][nf] = __builtin_amdgcn_mfma_f32_16x16x32_bf16(afh[mf], bql[nf], accW[mf][nf], 0, 0, 0);
                    accW[mf][nf] = __builtin_amdgcn_mfma_f32_16x16x32_bf16(afl[mf], bqh[nf], accW[mf][nf], 0, 0, 0);
                }
            asm volatile("s_waitcnt lgkmcnt(0)" ::: "memory");
            __builtin_amdgcn_s_barrier();
            asm volatile("" ::: "memory");
            cur ^= 1;
        }
    }

    #pragma unroll
    for (int mf = 0; mf < 4; ++mf)
        #pragma unroll
        for (int nf = 0; nf < 2; ++nf)
            #pragma unroll
            for (int r = 0; r < 4; ++r) {
                float v = accW[mf][nf][r];
                const int row = brow + wm * 64 + mf * 16 + ((l >> 4) << 2) + r;
                const int col = bn + wn * 32 + nf * 16 + (l & 15);
                size_t o = (size_t)row * SOUT + OFS + col;
                if (OUTM == 0) {
                    outF[o] = v;
                } else if (OUTM == 2) {
                    outF[o] = elu1(v);
                } else {
                    float ev = elu1(v);
                    unsigned short h = bfh(ev);
                    unsigned short lo = bfh(ev - bf2f(h));
                    outH[o] = h; outL[o] = lo;
                }
            }
}

// ---------- MoE layer: expert-inner loop, A staged once per k-step ----------
// out[row,col] = ELU( sum_e cf[row,e] * (sum_k A[row,k]*W[e][col,k] + bias[e,col]) )
// Abel fold: accW accumulates over e without reset; accT += (cf_e - cf_{e+1}) * accW.
// Bias: added into accW at ks==0 before each expert's MFMAs (telescopes to cf_e*bias_e).
template<int I_>
__global__ __launch_bounds__(256) void k_moe_fold(
    const unsigned short* __restrict__ Ah, const unsigned short* __restrict__ Al,
    const unsigned short* __restrict__ Bh, const unsigned short* __restrict__ Bl,
    const float* __restrict__ bias,   // [8][256]
    const float* __restrict__ coeff,  // [B][8]
    unsigned short* __restrict__ outH, unsigned short* __restrict__ outL)
{
    constexpr int KS = I_ / 32;
    constexpr int T  = KS * 8;
    __shared__ unsigned short sA[2][8192];   // per buf: hi 4096 shorts, lo 4096 (128 rows x 32k)
    __shared__ unsigned short sB[3][4096];   // per buf: hi 2048, lo 2048 (64 rows x 32k)
    __shared__ float cfd_s[8][128];          // cf[e]-cf[e+1] per row
    __shared__ float bias_s[8][64];

    const int tid = threadIdx.x, wid = tid >> 6, l = tid & 63;
    const int wm = wid >> 1, wn = wid & 1;
    const int brow = blockIdx.y * 128, bn = blockIdx.x * 64;

    for (int idx = tid; idx < 1024; idx += 256) {
        int r = idx >> 3, e = idx & 7;
        float v = coeff[(size_t)(brow + r) * 8 + e];
        float w = (e < 7) ? coeff[(size_t)(brow + r) * 8 + e + 1] : 0.0f;
        cfd_s[e][r] = v - w;
    }
    for (int idx = tid; idx < 512; idx += 256)
        bias_s[idx >> 6][idx & 63] = bias[(idx >> 6) * HID + bn + (idx & 63)];
    __syncthreads();   // cfd/bias visible before any frag reads; no vmem-lds in flight yet

    const int a_off  = (l >> 2) * I_ + (((l & 3) ^ ((l >> 3) & 3)) << 3);
    const int rd_off = ((l & 15) << 5) + (((l >> 4) ^ ((l >> 1) & 3)) << 3);

    const unsigned short* Abh = Ah + (size_t)brow * I_ + a_off;
    const unsigned short* Abl = Al + (size_t)brow * I_ + a_off;
    const unsigned short* Bbh = Bh + (size_t)bn * I_ + a_off;
    const unsigned short* Bbl = Bl + (size_t)bn * I_ + a_off;

    auto stage_A = [&](int ks, int bi) {     // 4 vmem instrs
        const unsigned short* ah = Abh + ks * 32;
        const unsigned short* al = Abl + ks * 32;
        unsigned short* buf = &sA[bi][0];
        gload16(ah + wid * 16 * I_,       buf + wid * 512);
        gload16(ah + (wid + 4) * 16 * I_, buf + (wid + 4) * 512);
        gload16(al + wid * 16 * I_,       buf + 4096 + wid * 512);
        gload16(al + (wid + 4) * 16 * I_, buf + 4096 + (wid + 4) * 512);
    };
    auto stage_B = [&](int t, int bi) {      // 2 vmem instrs
        const int ks = t >> 3, e = t & 7;
        const size_t eo = (size_t)e * HID * I_ + ks * 32;
        unsigned short* buf = &sB[bi][0];
        gload16(Bbh + eo + wid * 16 * I_, buf + wid * 512);
        gload16(Bbl + eo + wid * 16 * I_, buf + 2048 + wid * 512);
    };

    short8 afh[4], afl[4];
    f32x4 accT[4][2], accW[4][2];
    const f32x4 z4 = {0.f, 0.f, 0.f, 0.f};
    #pragma unroll
    for (int mf = 0; mf < 4; ++mf)
        #pragma unroll
        for (int nf = 0; nf < 2; ++nf) accT[mf][nf] = z4;

    // prologue: A(0) + B(0) + B(1) in flight (FIFO order matters for vmcnt math)
    stage_A(0, 0);
    stage_B(0, 0);
    stage_B(1, 1);

    int bcur = 0;
    for (int t = 0; t < T; ++t) {
        const int e = t & 7, ks = t >> 3;
        if (t + 2 < T) { int bi = bcur + 2; if (bi >= 3) bi -= 3; stage_B(t + 2, bi); }
        if (e == 0 && ks + 1 < KS) stage_A(ks + 1, (ks + 1) & 1);
        // exact newer-than-needed counts: A(ks+1) retires from the "newer" set after e==2
        if (e <= 2 && ks + 1 < KS)  { asm volatile("s_waitcnt vmcnt(8)" ::: "memory"); }
        else if (t + 2 < T)         { asm volatile("s_waitcnt vmcnt(4)" ::: "memory"); }
        else                        { asm volatile("s_waitcnt vmcnt(0)" ::: "memory"); }
        __builtin_amdgcn_s_barrier();
        asm volatile("" ::: "memory");

        if (e == 0) {
            const unsigned short* bpA = &sA[ks & 1][0];
            #pragma unroll
            for (int mf = 0; mf < 4; ++mf) {
                const int ro = (wm * 64 + mf * 16) * 32;
                afh[mf] = *(const short8*)(bpA + ro + rd_off);
                afl[mf] = *(const short8*)(bpA + 4096 + ro + rd_off);
            }
        }
        if (ks == 0) {
            #pragma unroll
            for (int nf = 0; nf < 2; ++nf) {
                float bv = bias_s[e][wn * 32 + nf * 16 + (l & 15)];
                #pragma unroll
                for (int mf = 0; mf < 4; ++mf) {
                    if (e == 0) { f32x4 b4 = {bv, bv, bv, bv}; accW[mf][nf] = b4; }
                    else {
                        accW[mf][nf][0] += bv; accW[mf][nf][1] += bv;
                        accW[mf][nf][2] += bv; accW[mf][nf][3] += bv;
                    }
                }
            }
        } else if (e == 0) {
            #pragma unroll
            for (int mf = 0; mf < 4; ++mf)
                #pragma unroll
                for (int nf = 0; nf < 2; ++nf) accW[mf][nf] = z4;
        }

        const unsigned short* bpB = &sB[bcur][0];
        short8 bqh[2], bql[2];
        #pragma unroll
        for (int nf = 0; nf < 2; ++nf) {
            const int ro = (wn * 32 + nf * 16) * 32;
            bqh[nf] = *(const short8*)(bpB + ro + rd_off);
            bql[nf] = *(const short8*)(bpB + 2048 + ro + rd_off);
        }
        #pragma unroll
        for (int mf = 0; mf < 4; ++mf)
            #pragma unroll
            for (int nf = 0; nf < 2; ++nf) {
                accW[mf][nf] = __builtin_amdgcn_mfma_f32_16x16x32_bf16(afh[mf], bqh[nf], accW[mf][nf], 0, 0, 0);
                accW[mf][nf] = __builtin_amdgcn_mfma_f32_16x16x32_bf16(afh[mf], bql[nf], accW[mf][nf], 0, 0, 0);
                accW[mf][nf] = __builtin_amdgcn_mfma_f32_16x16x32_bf16(afl[mf], bqh[nf], accW[mf][nf], 0, 0, 0);
            }
        // Abel fold
        #pragma unroll
        for (int mf = 0; mf < 4; ++mf) {
            f32x4 cv = *(const f32x4*)&cfd_s[e][wm * 64 + mf * 16 + ((l >> 4) << 2)];
            #pragma unroll
            for (int nf = 0; nf < 2; ++nf)
                #pragma unroll
                for (int r = 0; r < 4; ++r)
                    accT[mf][nf][r] += cv[r] * accW[mf][nf][r];
        }
        asm volatile("s_waitcnt lgkmcnt(0)" ::: "memory");
        __builtin_amdgcn_s_barrier();
        asm volatile("" ::: "memory");
        if (++bcur == 3) bcur = 0;
    }

    #pragma unroll
    for (int mf = 0; mf < 4; ++mf)
        #pragma unroll
        for (int nf = 0; nf < 2; ++nf)
            #pragma unroll
            for (int r = 0; r < 4; ++r) {
                const int row = brow + wm * 64 + mf * 16 + ((l >> 4) << 2) + r;
                const int col = bn + wn * 32 + nf * 16 + (l & 15);
                size_t o = (size_t)row * INTER + 32 + col;
                float ev = elu1(accT[mf][nf][r]);
                unsigned short h = bfh(ev);
                unsigned short lo = bfh(ev - bf2f(h));
                outH[o] = h; outL[o] = lo;
            }
}

// ---------- gate output layer + softmax over 8 experts (one wave/row) ----------
__global__ __launch_bounds__(256) void k_gate_out(
    const float* __restrict__ G2, const float* __restrict__ g2w,
    const float* __restrict__ g2b, float* __restrict__ coeff)
{
    __shared__ float wt[NE][GH];
    int tid = threadIdx.x;
    for (int idx = tid; idx < GH * NE; idx += 256) {
        int k = idx >> 3, e = idx & 7;
        wt[e][k] = g2w[idx];
    }
    __syncthreads();
    int row  = (blockIdx.x * 256 + tid) >> 6;
    int lane = tid & 63;
    if (row >= B_) return;
    float a0 = G2[(size_t)row * GH + lane];
    float a1 = G2[(size_t)row * GH + 64 + lane];
    float p[NE];
    #pragma unroll
    for (int e = 0; e < NE; ++e)
        p[e] = a0 * wt[e][lane] + a1 * wt[e][lane + 64];
    #pragma unroll
    for (int o = 32; o; o >>= 1) {
        #pragma unroll
        for (int e = 0; e < NE; ++e) p[e] += __shfl_xor(p[e], o);
    }
    float mx = -1e30f;
    #pragma unroll
    for (int e = 0; e < NE; ++e) { p[e] += g2b[e]; mx = fmaxf(mx, p[e]); }
    float s = 0.0f;
    #pragma unroll
    for (int e = 0; e < NE; ++e) { p[e] = expf(p[e] - mx); s += p[e]; }
    float inv = 1.0f / s;
    if (lane == 0) {
        #pragma unroll
        for (int e = 0; e < NE; ++e) coeff[(size_t)row * NE + e] = p[e] * inv;
    }
}

// ---------- final mix: out[b,o] = sum_e cf[b,e] * P[b, e*16+o] ----------
__global__ __launch_bounds__(256) void k_mix(
    const float* __restrict__ P, const float* __restrict__ cf, float* __restrict__ out)
{
    int id = blockIdx.x * 256 + threadIdx.x;
    if (id >= B_ * ACTD) return;
    int b = id >> 4, o = id & 15;
    const float* pr = P + (size_t)b * 128 + o;
    const float* cr = cf + (size_t)b * 8;
    float s = 0.f;
    #pragma unroll
    for (int e = 0; e < 8; ++e) s += cr[e] * pr[e * 16];
    out[id] = s;
}

extern "C" void kernel_launch(void* const* d_in, const int* in_sizes, int n_in,
                              void* d_out, int out_size, void* d_ws, size_t ws_size,
                              hipStream_t stream)
{
    (void)in_sizes; (void)n_in; (void)out_size; (void)ws_size;
    const float* z   = (const float*)d_in[0];
    const float* c   = (const float*)d_in[1];
    const float* w0  = (const float*)d_in[2];
    const float* b0  = (const float*)d_in[3];
    const float* w1  = (const float*)d_in[4];
    const float* b1  = (const float*)d_in[5];
    const float* w2  = (const float*)d_in[6];
    const float* b2  = (const float*)d_in[7];
    const float* g0w = (const float*)d_in[8];
    const float* g0b = (const float*)d_in[9];
    const float* g1w = (const float*)d_in[10];
    const float* g1b = (const float*)d_in[11];
    const float* g2w = (const float*)d_in[12];
    const float* g2b = (const float*)d_in[13];
    const float* lng = (const float*)d_in[14];
    const float* lnb = (const float*)d_in[15];
    float* out = (float*)d_out;

    char* p = (char*)d_ws;
    auto alloc = [&](size_t n) { char* r = p; p += (n + 255) & ~(size_t)255; return r; };
    unsigned short* X0h = (unsigned short*)alloc((size_t)B_ * IN0 * 2);
    unsigned short* X0l = (unsigned short*)alloc((size_t)B_ * IN0 * 2);
    unsigned short* X1h = (unsigned short*)alloc((size_t)B_ * INTER * 2);
    unsigned short* X1l = (unsigned short*)alloc((size_t)B_ * INTER * 2);
    unsigned short* X2h = (unsigned short*)alloc((size_t)B_ * INTER * 2);
    unsigned short* X2l = (unsigned short*)alloc((size_t)B_ * INTER * 2);
    unsigned short* G1h = (unsigned short*)alloc((size_t)B_ * GH * 2);
    unsigned short* G1l = (unsigned short*)alloc((size_t)B_ * GH * 2);
    float* G2f = (float*)alloc((size_t)B_ * GH * 4);      // reused as P2 after gate_out
    float* cf  = (float*)alloc((size_t)B_ * NE * 4);
    unsigned short* T0h = (unsigned short*)alloc((size_t)NE * IN0 * HID * 2);
    unsigned short* T0l = (unsigned short*)alloc((size_t)NE * IN0 * HID * 2);
    unsigned short* T1h = (unsigned short*)alloc((size_t)NE * INTER * HID * 2);
    unsigned short* T1l = (unsigned short*)alloc((size_t)NE * INTER * HID * 2);
    unsigned short* T2h = (unsigned short*)alloc((size_t)NE * INTER * ACTD * 2);
    unsigned short* T2l = (unsigned short*)alloc((size_t)NE * INTER * ACTD * 2);
    unsigned short* G0Th = (unsigned short*)alloc((size_t)IN0 * GH * 2);
    unsigned short* G0Tl = (unsigned short*)alloc((size_t)IN0 * GH * 2);
    unsigned short* G1Th = (unsigned short*)alloc((size_t)GH * GH * 2);
    unsigned short* G1Tl = (unsigned short*)alloc((size_t)GH * GH * 2);
    float* P2 = G2f;

    k_prep<<<dim3(3872), dim3(256), 0, stream>>>(w0, w1, w2, g0w, g1w,
        T0h, T0l, T1h, T1l, T2h, T2l, G0Th, G0Tl, G1Th, G1Tl);
    k_ln_concat2<<<dim3(B_ / 4), dim3(256), 0, stream>>>(z, c, lng, lnb,
        X0h, X0l, X1h, X1l, X2h, X2l);

    // gate MLP
    k_mfma_gemm<160, 128, 1, 1, 128, 0><<<dim3(2, 64), dim3(256), 0, stream>>>(
        X0h, X0l, G0Th, G0Tl, g0b, nullptr, nullptr, G1h, G1l);
    k_mfma_gemm<128, 128, 1, 2, 128, 0><<<dim3(2, 64), dim3(256), 0, stream>>>(
        G1h, G1l, G1Th, G1Tl, g1b, nullptr, G2f, nullptr, nullptr);
    k_gate_out<<<dim3(B_ / 4), dim3(256), 0, stream>>>(G2f, g2w, g2b, cf);

    // expert layers: A staged once per k-step, expert-inner fold
    k_moe_fold<160><<<dim3(4, 64), dim3(256), 0, stream>>>(
        X0h, X0l, T0h, T0l, b0, cf, X1h, X1l);
    k_moe_fold<288><<<dim3(4, 64), dim3(256), 0, stream>>>(
        X1h, X1l, T1h, T1l, b1, cf, X2h, X2l);
    // final layer as plain GEMM over N = E*16 = 128, then coeff-mix
    k_mfma_gemm<288, 128, 1, 0, 128, 0><<<dim3(2, 64), dim3(256), 0, stream>>>(
        X2h, X2l, T2h, T2l, b2, nullptr, P2, nullptr, nullptr);
    k_mix<<<dim3(B_ * ACTD / 256), dim3(256), 0, stream>>>(P2, cf, out);
}

// Round 4
// 129.163 us; speedup vs baseline: 1.3065x; 1.3065x over previous
//
#include <hip/hip_runtime.h>
#include <hip/hip_bf16.h>
#include <math.h>

#define B_     8192
#define LATENT 32
#define CIN    128
#define HID    256
#define ACTD   16
#define NE     8
#define GH     128
#define IN0    160   // LATENT + CIN
#define INTER  288   // HID + LATENT

typedef __attribute__((ext_vector_type(8))) short short8;
typedef __attribute__((ext_vector_type(4))) float f32x4;
typedef __attribute__((ext_vector_type(4))) int   i32x4;

__device__ __forceinline__ float elu1(float x) { return x > 0.0f ? x : expm1f(x); }

__device__ __forceinline__ unsigned short bfh(float v) {
    __hip_bfloat16 b = __float2bfloat16(v);
    return *reinterpret_cast<unsigned short*>(&b);
}
__device__ __forceinline__ float bf2f(unsigned short u) {
    __hip_bfloat16 b;
    *reinterpret_cast<unsigned short*>(&b) = u;
    return __bfloat162float(b);
}
__device__ __forceinline__ void gload16(const unsigned short* g, unsigned short* lds) {
    __builtin_amdgcn_global_load_lds((const __attribute__((address_space(1))) void*)g,
                                     (__attribute__((address_space(3))) void*)lds, 16, 0, 0);
}
__device__ __forceinline__ short8 as_s8(i32x4 v) {
    union U { i32x4 a; short8 b; } u; u.a = v; return u.b;
}

// ---------- prep: transpose + hi/lo split all weight matrices ----------
__global__ __launch_bounds__(256) void k_prep(
    const float* __restrict__ w0, const float* __restrict__ w1, const float* __restrict__ w2,
    const float* __restrict__ g0w, const float* __restrict__ g1w,
    unsigned short* __restrict__ T0h, unsigned short* __restrict__ T0l,
    unsigned short* __restrict__ T1h, unsigned short* __restrict__ T1l,
    unsigned short* __restrict__ T2h, unsigned short* __restrict__ T2l,
    unsigned short* __restrict__ G0h, unsigned short* __restrict__ G0l,
    unsigned short* __restrict__ G1h, unsigned short* __restrict__ G1l)
{
    int id = blockIdx.x * 256 + threadIdx.x;
    float v; size_t dst; unsigned short *H, *L;
    if (id < 327680) {
        int o = id & 255, ei = id >> 8, i = ei % 160, e = ei / 160;
        v = w0[id]; H = T0h; L = T0l; dst = (size_t)(e * 256 + o) * 160 + i;
    } else if (id < 917504) {
        int t = id - 327680;
        int o = t & 255, ei = t >> 8, i = ei % 288, e = ei / 288;
        v = w1[t]; H = T1h; L = T1l; dst = (size_t)(e * 256 + o) * 288 + i;
    } else if (id < 954368) {
        int t = id - 917504;
        int o = t & 15, ei = t >> 4, i = ei % 288, e = ei / 288;
        v = w2[t]; H = T2h; L = T2l; dst = (size_t)(e * 16 + o) * 288 + i;
    } else if (id < 974848) {
        int t = id - 954368;
        int o = t & 127, i = t >> 7;
        v = g0w[t]; H = G0h; L = G0l; dst = (size_t)o * 160 + i;
    } else if (id < 991232) {
        int t = id - 974848;
        int o = t & 127, i = t >> 7;
        v = g1w[t]; H = G1h; L = G1l; dst = (size_t)o * 128 + i;
    } else return;
    unsigned short h = bfh(v);
    unsigned short lo = bfh(v - bf2f(h));
    H[dst] = h; L[dst] = lo;
}

// ---------- LayerNorm + concat, split to hi/lo; also seed z into X1/X2 ----------
__global__ __launch_bounds__(256) void k_ln_concat2(
    const float* __restrict__ z, const float* __restrict__ c,
    const float* __restrict__ g, const float* __restrict__ bt,
    unsigned short* __restrict__ X0h, unsigned short* __restrict__ X0l,
    unsigned short* __restrict__ X1h, unsigned short* __restrict__ X1l,
    unsigned short* __restrict__ X2h, unsigned short* __restrict__ X2l)
{
    int gid = blockIdx.x * 256 + threadIdx.x;
    int row = gid >> 6;
    int l = threadIdx.x & 63;
    if (row >= B_) return;
    const float* cr = c + (size_t)row * CIN;
    float v0 = cr[l], v1 = cr[l + 64];
    float s = v0 + v1;
    #pragma unroll
    for (int o = 32; o; o >>= 1) s += __shfl_xor(s, o);
    float mean = s * (1.0f / 128.0f);
    float d0 = v0 - mean, d1 = v1 - mean;
    float q = d0 * d0 + d1 * d1;
    #pragma unroll
    for (int o = 32; o; o >>= 1) q += __shfl_xor(q, o);
    float rstd = rsqrtf(q * (1.0f / 128.0f) + 1e-5f);
    float y0 = d0 * rstd * g[l] + bt[l];
    float y1 = d1 * rstd * g[l + 64] + bt[l + 64];
    size_t r0 = (size_t)row * IN0;
    unsigned short h0 = bfh(y0), lo0 = bfh(y0 - bf2f(h0));
    unsigned short h1 = bfh(y1), lo1 = bfh(y1 - bf2f(h1));
    X0h[r0 + 32 + l] = h0; X0l[r0 + 32 + l] = lo0;
    X0h[r0 + 96 + l] = h1; X0l[r0 + 96 + l] = lo1;
    if (l < LATENT) {
        float zv = z[(size_t)row * LATENT + l];
        unsigned short zh = bfh(zv), zl = bfh(zv - bf2f(zh));
        X0h[r0 + l] = zh; X0l[r0 + l] = zl;
        size_t r1 = (size_t)row * INTER;
        X1h[r1 + l] = zh; X1l[r1 + l] = zl;
        X2h[r1 + l] = zh; X2l[r1 + l] = zl;
    }
}

// ---------- register-A hi/lo-split MFMA GEMM, e-outer, B through 4 LDS bufs ----------
// Block: 256 thr = 4 waves (2x2), tile 64 rows x 64 cols; wave-tile 32x32 (mf2,nf2).
// A [M][K] hi/lo held in VGPRs for the whole kernel (loaded direct from global).
// B [rows = e*HID + col][K] transposed hi/lo, staged 64col x 32k per phase.
// NE_T>1: per-expert accW folded into accT with coeff (+bias) after each expert.
// OUTM: 0 = fp32 raw(+bias); 1 = ELU + hi/lo bf16 split; 2 = fp32 + ELU.
template<int KS, int NE_T, int OUTM, int SOUT, int OFS, int CPX>
__global__ __launch_bounds__(256, 2) void k_reg_gemm(
    const unsigned short* __restrict__ Ah, const unsigned short* __restrict__ Al,
    const unsigned short* __restrict__ Bh, const unsigned short* __restrict__ Bl,
    const float* __restrict__ bias, const float* __restrict__ coeff,
    float* __restrict__ outF, unsigned short* __restrict__ outH,
    unsigned short* __restrict__ outL)
{
    constexpr int K = KS * 32;
    constexpr int T = KS * NE_T;
    __shared__ unsigned short sB[4][4096];   // per buf 8KB: hi 2048 shorts, lo 2048
    __shared__ float cf_s[8][64];
    __shared__ float bias_s[NE_T][64];

    const int tid = threadIdx.x, wid = tid >> 6, l = tid & 63;
    const int wm = wid >> 1, wn = wid & 1;
    // XCD-bijective swizzle: each XCD owns one 64-col weight slice + contiguous rows
    const int bid = blockIdx.x;
    const int m = (bid & 7) * CPX + (bid >> 3);
    const int brow = (m & 127) * 64, bn = (m >> 7) * 64;

    if (NE_T > 1) {
        for (int idx = tid; idx < 512; idx += 256)
            cf_s[idx & 7][idx >> 3] = coeff[(size_t)(brow + (idx >> 3)) * 8 + (idx & 7)];
    }
    for (int idx = tid; idx < NE_T * 64; idx += 256)
        bias_s[idx >> 6][idx & 63] = bias[(idx >> 6) * HID + bn + (idx & 63)];

    // ---- A fragments: direct global -> VGPR, MFMA layout (row=l&15, chunk=l>>4) ----
    const unsigned short* Arh = Ah + (size_t)(brow + wm * 32 + (l & 15)) * K + (l >> 4) * 8;
    const unsigned short* Arl = Al + (size_t)(brow + wm * 32 + (l & 15)) * K + (l >> 4) * 8;
    i32x4 a_h[KS][2], a_l[KS][2];
    #pragma unroll
    for (int ks = 0; ks < KS; ++ks)
        #pragma unroll
        for (int mf = 0; mf < 2; ++mf) {
            a_h[ks][mf] = *(const i32x4*)(Arh + (size_t)mf * 16 * K + ks * 32);
            a_l[ks][mf] = *(const i32x4*)(Arl + (size_t)mf * 16 * K + ks * 32);
        }

    // ---- B staging (proven swizzled-source pattern; wave covers 16 rows/1KB) ----
    const int b_off = (l >> 2) * K + (((l & 3) ^ ((l >> 3) & 3)) << 3);
    const unsigned short* Bbh = Bh + (size_t)bn * K + b_off + (size_t)wid * 16 * K;
    const unsigned short* Bbl = Bl + (size_t)bn * K + b_off + (size_t)wid * 16 * K;
    int se = 0, sk = 0, bnext = 0;
    auto stage = [&]() {
        unsigned short* buf = &sB[bnext][0];
        const size_t off = (size_t)se * HID * K + sk * 32;
        gload16(Bbh + off, buf + wid * 512);
        gload16(Bbl + off, buf + 2048 + wid * 512);
        if (++sk == KS) { sk = 0; ++se; }
        bnext = (bnext + 1) & 3;
    };
    stage(); stage(); stage();                       // bufs 0..2 in flight

    asm volatile("s_waitcnt vmcnt(0)" ::: "memory"); // drain A + prologue stages once
    #pragma unroll
    for (int ks = 0; ks < KS; ++ks)
        #pragma unroll
        for (int mf = 0; mf < 2; ++mf) {             // launder: hide A from waitcnt pass
            asm volatile("" : "+v"(a_h[ks][mf]));
            asm volatile("" : "+v"(a_l[ks][mf]));
        }

    const int rd_off = ((l & 15) << 5) + (((l >> 4) ^ ((l >> 1) & 3)) << 3);
    f32x4 accT[2][2], accW[2][2];
    const f32x4 z4 = {0.f, 0.f, 0.f, 0.f};
    if (NE_T > 1) {
        #pragma unroll
        for (int mf = 0; mf < 2; ++mf)
            #pragma unroll
            for (int nf = 0; nf < 2; ++nf) accT[mf][nf] = z4;
    }

    int t = 0, bcur = 0;
    for (int e = 0; e < NE_T; ++e) {
        #pragma unroll
        for (int mf = 0; mf < 2; ++mf)
            #pragma unroll
            for (int nf = 0; nf < 2; ++nf) accW[mf][nf] = z4;

        #pragma unroll
        for (int ks = 0; ks < KS; ++ks, ++t) {
            if (t + 3 < T) stage();
            const int rem = T - 1 - t;
            if (rem >= 3)      { asm volatile("s_waitcnt vmcnt(6)" ::: "memory"); }
            else if (rem == 2) { asm volatile("s_waitcnt vmcnt(4)" ::: "memory"); }
            else if (rem == 1) { asm volatile("s_waitcnt vmcnt(2)" ::: "memory"); }
            else               { asm volatile("s_waitcnt vmcnt(0)" ::: "memory"); }
            __builtin_amdgcn_s_barrier();
            __builtin_amdgcn_sched_barrier(0);

            const unsigned short* bp = &sB[bcur][0];
            short8 bqh[2], bql[2];
            #pragma unroll
            for (int nf = 0; nf < 2; ++nf) {
                const int ro = (wn * 32 + nf * 16) * 32;
                bqh[nf] = *(const short8*)(bp + ro + rd_off);
                bql[nf] = *(const short8*)(bp + 2048 + ro + rd_off);
            }
            #pragma unroll
            for (int mf = 0; mf < 2; ++mf)
                #pragma unroll
                for (int nf = 0; nf < 2; ++nf) {
                    accW[mf][nf] = __builtin_amdgcn_mfma_f32_16x16x32_bf16(as_s8(a_h[ks][mf]), bqh[nf], accW[mf][nf], 0, 0, 0);
                    accW[mf][nf] = __builtin_amdgcn_mfma_f32_16x16x32_bf16(as_s8(a_h[ks][mf]), bql[nf], accW[mf][nf], 0, 0, 0);
                    accW[mf][nf] = __builtin_amdgcn_mfma_f32_16x16x32_bf16(as_s8(a_l[ks][mf]), bqh[nf], accW[mf][nf], 0, 0, 0);
                }

            asm volatile("s_waitcnt lgkmcnt(0)" ::: "memory");
            __builtin_amdgcn_sched_barrier(0);
            __builtin_amdgcn_s_barrier();
            bcur = (bcur + 1) & 3;
        }

        if (NE_T > 1) {
            #pragma unroll
            for (int mf = 0; mf < 2; ++mf) {
                f32x4 cv = *(const f32x4*)&cf_s[e][wm * 32 + mf * 16 + ((l >> 4) << 2)];
                #pragma unroll
                for (int nf = 0; nf < 2; ++nf) {
                    float bv = bias_s[e][wn * 32 + nf * 16 + (l & 15)];
                    #pragma unroll
                    for (int r = 0; r < 4; ++r)
                        accT[mf][nf][r] += cv[r] * (accW[mf][nf][r] + bv);
                }
            }
        }
    }

    #pragma unroll
    for (int mf = 0; mf < 2; ++mf)
        #pragma unroll
        for (int nf = 0; nf < 2; ++nf) {
            float bv = (NE_T > 1) ? 0.0f : bias_s[0][wn * 32 + nf * 16 + (l & 15)];
            #pragma unroll
            for (int r = 0; r < 4; ++r) {
                float v = (NE_T > 1) ? accT[mf][nf][r] : (accW[mf][nf][r] + bv);
                const int row = brow + wm * 32 + mf * 16 + ((l >> 4) << 2) + r;
                const int col = bn + wn * 32 + nf * 16 + (l & 15);
                size_t o = (size_t)row * SOUT + OFS + col;
                if (OUTM == 0) {
                    outF[o] = v;
                } else if (OUTM == 2) {
                    outF[o] = elu1(v);
                } else {
                    float ev = elu1(v);
                    unsigned short h = bfh(ev);
                    unsigned short lo = bfh(ev - bf2f(h));
                    outH[o] = h; outL[o] = lo;
                }
            }
        }
}

// ---------- gate output layer + softmax over 8 experts (one wave/row) ----------
__global__ __launch_bounds__(256) void k_gate_out(
    const float* __restrict__ G2, const float* __restrict__ g2w,
    const float* __restrict__ g2b, float* __restrict__ coeff)
{
    __shared__ float wt[NE][GH];
    int tid = threadIdx.x;
    for (int idx = tid; idx < GH * NE; idx += 256) {
        int k = idx >> 3, e = idx & 7;
        wt[e][k] = g2w[idx];
    }
    __syncthreads();
    int row  = (blockIdx.x * 256 + tid) >> 6;
    int lane = tid & 63;
    if (row >= B_) return;
    float a0 = G2[(size_t)row * GH + lane];
    float a1 = G2[(size_t)row * GH + 64 + lane];
    float p[NE];
    #pragma unroll
    for (int e = 0; e < NE; ++e)
        p[e] = a0 * wt[e][lane] + a1 * wt[e][lane + 64];
    #pragma unroll
    for (int o = 32; o; o >>= 1) {
        #pragma unroll
        for (int e = 0; e < NE; ++e) p[e] += __shfl_xor(p[e], o);
    }
    float mx = -1e30f;
    #pragma unroll
    for (int e = 0; e < NE; ++e) { p[e] += g2b[e]; mx = fmaxf(mx, p[e]); }
    float s = 0.0f;
    #pragma unroll
    for (int e = 0; e < NE; ++e) { p[e] = expf(p[e] - mx); s += p[e]; }
    float inv = 1.0f / s;
    if (lane == 0) {
        #pragma unroll
        for (int e = 0; e < NE; ++e) coeff[(size_t)row * NE + e] = p[e] * inv;
    }
}

// ---------- final mix: out[b,o] = sum_e cf[b,e] * P[b, e*16+o] ----------
__global__ __launch_bounds__(256) void k_mix(
    const float* __restrict__ P, const float* __restrict__ cf, float* __restrict__ out)
{
    int id = blockIdx.x * 256 + threadIdx.x;
    if (id >= B_ * ACTD) return;
    int b = id >> 4, o = id & 15;
    const float* pr = P + (size_t)b * 128 + o;
    const float* cr = cf + (size_t)b * 8;
    float s = 0.f;
    #pragma unroll
    for (int e = 0; e < 8; ++e) s += cr[e] * pr[e * 16];
    out[id] = s;
}

extern "C" void kernel_launch(void* const* d_in, const int* in_sizes, int n_in,
                              void* d_out, int out_size, void* d_ws, size_t ws_size,
                              hipStream_t stream)
{
    (void)in_sizes; (void)n_in; (void)out_size; (void)ws_size;
    const float* z   = (const float*)d_in[0];
    const float* c   = (const float*)d_in[1];
    const float* w0  = (const float*)d_in[2];
    const float* b0  = (const float*)d_in[3];
    const float* w1  = (const float*)d_in[4];
    const float* b1  = (const float*)d_in[5];
    const float* w2  = (const float*)d_in[6];
    const float* b2  = (const float*)d_in[7];
    const float* g0w = (const float*)d_in[8];
    const float* g0b = (const float*)d_in[9];
    const float* g1w = (const float*)d_in[10];
    const float* g1b = (const float*)d_in[11];
    const float* g2w = (const float*)d_in[12];
    const float* g2b = (const float*)d_in[13];
    const float* lng = (const float*)d_in[14];
    const float* lnb = (const float*)d_in[15];
    float* out = (float*)d_out;

    char* p = (char*)d_ws;
    auto alloc = [&](size_t n) { char* r = p; p += (n + 255) & ~(size_t)255; return r; };
    unsigned short* X0h = (unsigned short*)alloc((size_t)B_ * IN0 * 2);
    unsigned short* X0l = (unsigned short*)alloc((size_t)B_ * IN0 * 2);
    unsigned short* X1h = (unsigned short*)alloc((size_t)B_ * INTER * 2);
    unsigned short* X1l = (unsigned short*)alloc((size_t)B_ * INTER * 2);
    unsigned short* X2h = (unsigned short*)alloc((size_t)B_ * INTER * 2);
    unsigned short* X2l = (unsigned short*)alloc((size_t)B_ * INTER * 2);
    unsigned short* G1h = (unsigned short*)alloc((size_t)B_ * GH * 2);
    unsigned short* G1l = (unsigned short*)alloc((size_t)B_ * GH * 2);
    float* G2f = (float*)alloc((size_t)B_ * GH * 4);      // reused as P2 after gate_out
    float* cf  = (float*)alloc((size_t)B_ * NE * 4);
    unsigned short* T0h = (unsigned short*)alloc((size_t)NE * IN0 * HID * 2);
    unsigned short* T0l = (unsigned short*)alloc((size_t)NE * IN0 * HID * 2);
    unsigned short* T1h = (unsigned short*)alloc((size_t)NE * INTER * HID * 2);
    unsigned short* T1l = (unsigned short*)alloc((size_t)NE * INTER * HID * 2);
    unsigned short* T2h = (unsigned short*)alloc((size_t)NE * INTER * ACTD * 2);
    unsigned short* T2l = (unsigned short*)alloc((size_t)NE * INTER * ACTD * 2);
    unsigned short* G0Th = (unsigned short*)alloc((size_t)IN0 * GH * 2);
    unsigned short* G0Tl = (unsigned short*)alloc((size_t)IN0 * GH * 2);
    unsigned short* G1Th = (unsigned short*)alloc((size_t)GH * GH * 2);
    unsigned short* G1Tl = (unsigned short*)alloc((size_t)GH * GH * 2);
    float* P2 = G2f;

    k_prep<<<dim3(3872), dim3(256), 0, stream>>>(w0, w1, w2, g0w, g1w,
        T0h, T0l, T1h, T1l, T2h, T2l, G0Th, G0Tl, G1Th, G1Tl);
    k_ln_concat2<<<dim3(B_ / 4), dim3(256), 0, stream>>>(z, c, lng, lnb,
        X0h, X0l, X1h, X1l, X2h, X2l);

    // gate MLP: X0 -> G1 (bf16 hi/lo) -> G2f (fp32) -> coeff
    k_reg_gemm<5, 1, 1, 128, 0, 32><<<dim3(256), dim3(256), 0, stream>>>(
        X0h, X0l, G0Th, G0Tl, g0b, nullptr, nullptr, G1h, G1l);
    k_reg_gemm<4, 1, 2, 128, 0, 32><<<dim3(256), dim3(256), 0, stream>>>(
        G1h, G1l, G1Th, G1Tl, g1b, nullptr, G2f, nullptr, nullptr);
    k_gate_out<<<dim3(B_ / 4), dim3(256), 0, stream>>>(G2f, g2w, g2b, cf);

    // expert layers: A in registers, e-outer, per-expert fold with coeff
    k_reg_gemm<5, 8, 1, 288, 32, 64><<<dim3(512), dim3(256), 0, stream>>>(
        X0h, X0l, T0h, T0l, b0, cf, nullptr, X1h, X1l);
    k_reg_gemm<9, 8, 1, 288, 32, 64><<<dim3(512), dim3(256), 0, stream>>>(
        X1h, X1l, T1h, T1l, b1, cf, nullptr, X2h, X2l);
    // final layer as plain GEMM over N = E*16 = 128, then coeff-mix
    k_reg_gemm<9, 1, 0, 128, 0, 32><<<dim3(256), dim3(256), 0, stream>>>(
        X2h, X2l, T2h, T2l, b2, nullptr, P2, nullptr, nullptr);
    k_mix<<<dim3(B_ * ACTD / 256), dim3(256), 0, stream>>>(P2, cf, out);
}

// Round 5
// 116.832 us; speedup vs baseline: 1.4443x; 1.1055x over previous
//
#include <hip/hip_runtime.h>
#include <hip/hip_bf16.h>
#include <math.h>

#define B_     8192
#define LATENT 32
#define CIN    128
#define HID    256
#define ACTD   16
#define NE     8
#define GH     128
#define IN0    160   // LATENT + CIN
#define INTER  288   // HID + LATENT

typedef __attribute__((ext_vector_type(8))) short short8;
typedef __attribute__((ext_vector_type(4))) float f32x4;
typedef __attribute__((ext_vector_type(4))) int   i32x4;

__device__ __forceinline__ float elu1(float x) { return x > 0.0f ? x : expm1f(x); }

__device__ __forceinline__ unsigned short bfh(float v) {
    __hip_bfloat16 b = __float2bfloat16(v);
    return *reinterpret_cast<unsigned short*>(&b);
}
__device__ __forceinline__ float bf2f(unsigned short u) {
    __hip_bfloat16 b;
    *reinterpret_cast<unsigned short*>(&b) = u;
    return __bfloat162float(b);
}
__device__ __forceinline__ void gload16(const unsigned short* g, const char* lds) {
    __builtin_amdgcn_global_load_lds((const __attribute__((address_space(1))) void*)g,
                                     (__attribute__((address_space(3))) void*)lds, 16, 0, 0);
}
__device__ __forceinline__ short8 as_s8(i32x4 v) {
    union U { i32x4 a; short8 b; } u; u.a = v; return u.b;
}

// ---------- prep: transpose + hi/lo split all weight matrices ----------
__global__ __launch_bounds__(256) void k_prep(
    const float* __restrict__ w0, const float* __restrict__ w1, const float* __restrict__ w2,
    const float* __restrict__ g0w, const float* __restrict__ g1w,
    unsigned short* __restrict__ T0h, unsigned short* __restrict__ T0l,
    unsigned short* __restrict__ T1h, unsigned short* __restrict__ T1l,
    unsigned short* __restrict__ T2h, unsigned short* __restrict__ T2l,
    unsigned short* __restrict__ G0h, unsigned short* __restrict__ G0l,
    unsigned short* __restrict__ G1h, unsigned short* __restrict__ G1l)
{
    int id = blockIdx.x * 256 + threadIdx.x;
    float v; size_t dst; unsigned short *H, *L;
    if (id < 327680) {
        int o = id & 255, ei = id >> 8, i = ei % 160, e = ei / 160;
        v = w0[id]; H = T0h; L = T0l; dst = (size_t)(e * 256 + o) * 160 + i;
    } else if (id < 917504) {
        int t = id - 327680;
        int o = t & 255, ei = t >> 8, i = ei % 288, e = ei / 288;
        v = w1[t]; H = T1h; L = T1l; dst = (size_t)(e * 256 + o) * 288 + i;
    } else if (id < 954368) {
        int t = id - 917504;
        int o = t & 15, ei = t >> 4, i = ei % 288, e = ei / 288;
        v = w2[t]; H = T2h; L = T2l; dst = (size_t)(e * 16 + o) * 288 + i;
    } else if (id < 974848) {
        int t = id - 954368;
        int o = t & 127, i = t >> 7;
        v = g0w[t]; H = G0h; L = G0l; dst = (size_t)o * 160 + i;
    } else if (id < 991232) {
        int t = id - 974848;
        int o = t & 127, i = t >> 7;
        v = g1w[t]; H = G1h; L = G1l; dst = (size_t)o * 128 + i;
    } else return;
    unsigned short h = bfh(v);
    unsigned short lo = bfh(v - bf2f(h));
    H[dst] = h; L[dst] = lo;
}

// ---------- LayerNorm + concat, split to hi/lo; also seed z into X1/X2 ----------
__global__ __launch_bounds__(256) void k_ln_concat2(
    const float* __restrict__ z, const float* __restrict__ c,
    const float* __restrict__ g, const float* __restrict__ bt,
    unsigned short* __restrict__ X0h, unsigned short* __restrict__ X0l,
    unsigned short* __restrict__ X1h, unsigned short* __restrict__ X1l,
    unsigned short* __restrict__ X2h, unsigned short* __restrict__ X2l)
{
    int gid = blockIdx.x * 256 + threadIdx.x;
    int row = gid >> 6;
    int l = threadIdx.x & 63;
    if (row >= B_) return;
    const float* cr = c + (size_t)row * CIN;
    float v0 = cr[l], v1 = cr[l + 64];
    float s = v0 + v1;
    #pragma unroll
    for (int o = 32; o; o >>= 1) s += __shfl_xor(s, o);
    float mean = s * (1.0f / 128.0f);
    float d0 = v0 - mean, d1 = v1 - mean;
    float q = d0 * d0 + d1 * d1;
    #pragma unroll
    for (int o = 32; o; o >>= 1) q += __shfl_xor(q, o);
    float rstd = rsqrtf(q * (1.0f / 128.0f) + 1e-5f);
    float y0 = d0 * rstd * g[l] + bt[l];
    float y1 = d1 * rstd * g[l + 64] + bt[l + 64];
    size_t r0 = (size_t)row * IN0;
    unsigned short h0 = bfh(y0), lo0 = bfh(y0 - bf2f(h0));
    unsigned short h1 = bfh(y1), lo1 = bfh(y1 - bf2f(h1));
    X0h[r0 + 32 + l] = h0; X0l[r0 + 32 + l] = lo0;
    X0h[r0 + 96 + l] = h1; X0l[r0 + 96 + l] = lo1;
    if (l < LATENT) {
        float zv = z[(size_t)row * LATENT + l];
        unsigned short zh = bfh(zv), zl = bfh(zv - bf2f(zh));
        X0h[r0 + l] = zh; X0l[r0 + l] = zl;
        size_t r1 = (size_t)row * INTER;
        X1h[r1 + l] = zh; X1l[r1 + l] = zl;
        X2h[r1 + l] = zh; X2l[r1 + l] = zl;
    }
}

// ---------- MoE layer: expert-parallel waves, big MFMA clusters ----------
// Block: 256 thr / 4 waves. Tile: 64 rows x 32 cols. Wave w computes experts
// 2w, 2w+1 over the FULL tile (acc[2][4mf][2nf]). Per 32-k phase: A(8KB) +
// all-experts B(32KB) staged double-buffered; 48 MFMAs/wave between barriers.
// Epilogue: cf-scaled partials reduced across waves via LDS.
template<int KS>
__global__ __launch_bounds__(256, 2) void k_moe_epar(
    const unsigned short* __restrict__ Ah, const unsigned short* __restrict__ Al,
    const unsigned short* __restrict__ Bh, const unsigned short* __restrict__ Bl,
    const float* __restrict__ bias,   // [8][256]
    const float* __restrict__ coeff,  // [B][8]
    unsigned short* __restrict__ outH, unsigned short* __restrict__ outL)
{
    constexpr int K = KS * 32;
    __shared__ __align__(16) char smem[81920];   // 2 bufs x (A 8KB + B 32KB)

    const int tid = threadIdx.x, wid = tid >> 6, l = tid & 63;
    const int brow = (blockIdx.x >> 3) * 64;
    const int bn   = (blockIdx.x & 7) * 32;      // each XCD -> one col slice

    // staging source pointers (16-row units, proven inverse-swizzled source)
    const int swz = (((l & 3) ^ ((l >> 3) & 3)) << 3);
    const int rq  = l >> 2;
    const unsigned short* sA[2];
    sA[0] = Ah + (size_t)(brow + wid * 16 + rq) * K + swz;
    sA[1] = Al + (size_t)(brow + wid * 16 + rq) * K + swz;
    const unsigned short* sB2[2][2];
    #pragma unroll
    for (int e2 = 0; e2 < 2; ++e2) {
        sB2[e2][0] = Bh + (size_t)((2 * wid + e2) * HID + bn + rq) * K + swz;
        sB2[e2][1] = Bl + (size_t)((2 * wid + e2) * HID + bn + rq) * K + swz;
    }

    auto stage = [&](int bi, int k0) {   // 10 gload16 per lane
        char* buf = smem + bi * 40960;
        #pragma unroll
        for (int h = 0; h < 2; ++h)
            gload16(sA[h] + k0, buf + h * 4096 + wid * 1024);
        #pragma unroll
        for (int e2 = 0; e2 < 2; ++e2)
            #pragma unroll
            for (int h = 0; h < 2; ++h)
                #pragma unroll
                for (int g = 0; g < 2; ++g)
                    gload16(sB2[e2][h] + g * 16 * K + k0,
                            buf + 8192 + (2 * wid + e2) * 4096 + h * 2048 + g * 1024);
    };

    const int rdo = ((l & 15) << 6) + (((l >> 4) ^ ((l >> 1) & 3)) << 4);  // bytes in 16-row unit
    f32x4 acc[2][4][2];
    #pragma unroll
    for (int e2 = 0; e2 < 2; ++e2)
        #pragma unroll
        for (int mf = 0; mf < 4; ++mf)
            #pragma unroll
            for (int nf = 0; nf < 2; ++nf) acc[e2][mf][nf] = (f32x4){0.f, 0.f, 0.f, 0.f};

    stage(0, 0);
    __syncthreads();   // full drain: buf0 ready

    for (int t = 0; t < KS; ++t) {
        if (t + 1 < KS) {
            stage((t + 1) & 1, (t + 1) * 32);
            asm volatile("s_waitcnt vmcnt(10)" ::: "memory");  // phase-t loads done
        } else {
            asm volatile("s_waitcnt vmcnt(0)" ::: "memory");
        }
        __builtin_amdgcn_s_barrier();
        __builtin_amdgcn_sched_barrier(0);

        const char* buf = smem + (t & 1) * 40960;
        short8 afh[4], afl[4];
        #pragma unroll
        for (int mf = 0; mf < 4; ++mf) {
            afh[mf] = *(const short8*)(buf + mf * 1024 + rdo);
            afl[mf] = *(const short8*)(buf + 4096 + mf * 1024 + rdo);
        }
        #pragma unroll
        for (int e2 = 0; e2 < 2; ++e2) {
            const char* be = buf + 8192 + (2 * wid + e2) * 4096;
            short8 bh0 = *(const short8*)(be + rdo);
            short8 bh1 = *(const short8*)(be + 1024 + rdo);
            short8 bl0 = *(const short8*)(be + 2048 + rdo);
            short8 bl1 = *(const short8*)(be + 3072 + rdo);
            #pragma unroll
            for (int mf = 0; mf < 4; ++mf) {
                acc[e2][mf][0] = __builtin_amdgcn_mfma_f32_16x16x32_bf16(afh[mf], bh0, acc[e2][mf][0], 0, 0, 0);
                acc[e2][mf][0] = __builtin_amdgcn_mfma_f32_16x16x32_bf16(afh[mf], bl0, acc[e2][mf][0], 0, 0, 0);
                acc[e2][mf][0] = __builtin_amdgcn_mfma_f32_16x16x32_bf16(afl[mf], bh0, acc[e2][mf][0], 0, 0, 0);
                acc[e2][mf][1] = __builtin_amdgcn_mfma_f32_16x16x32_bf16(afh[mf], bh1, acc[e2][mf][1], 0, 0, 0);
                acc[e2][mf][1] = __builtin_amdgcn_mfma_f32_16x16x32_bf16(afh[mf], bl1, acc[e2][mf][1], 0, 0, 0);
                acc[e2][mf][1] = __builtin_amdgcn_mfma_f32_16x16x32_bf16(afl[mf], bh1, acc[e2][mf][1], 0, 0, 0);
            }
        }
        asm volatile("s_waitcnt lgkmcnt(0)" ::: "memory");
        __builtin_amdgcn_sched_barrier(0);
        __builtin_amdgcn_s_barrier();
    }

    // ---- epilogue: cf table -> LDS, scale partials, cross-wave reduce ----
    float* cfl = (float*)(smem + 73728);             // [64][8]
    if (tid < 128) {
        f32x4 v = *(const f32x4*)&coeff[(size_t)(brow + (tid >> 1)) * 8 + (tid & 1) * 4];
        *(f32x4*)&cfl[tid * 4] = v;
    }
    __syncthreads();

    const int e0 = 2 * wid, e1 = 2 * wid + 1;
    float bv0[2], bv1[2];
    #pragma unroll
    for (int nf = 0; nf < 2; ++nf) {
        bv0[nf] = bias[e0 * HID + bn + nf * 16 + (l & 15)];
        bv1[nf] = bias[e1 * HID + bn + nf * 16 + (l & 15)];
    }
    float* red = (float*)smem;                        // [4][64][36]
    #pragma unroll
    for (int mf = 0; mf < 4; ++mf) {
        const int rb = mf * 16 + ((l >> 4) << 2);
        #pragma unroll
        for (int r = 0; r < 4; ++r) {
            float c0 = cfl[(rb + r) * 8 + e0];
            float c1 = cfl[(rb + r) * 8 + e1];
            #pragma unroll
            for (int nf = 0; nf < 2; ++nf) {
                float s = (acc[0][mf][nf][r] + bv0[nf]) * c0
                        + (acc[1][mf][nf][r] + bv1[nf]) * c1;
                red[wid * 2304 + (rb + r) * 36 + nf * 16 + (l & 15)] = s;
            }
        }
    }
    __syncthreads();

    const int row = tid >> 2, c0_ = (tid & 3) * 8;
    f32x4 s0 = {0.f, 0.f, 0.f, 0.f}, s1 = {0.f, 0.f, 0.f, 0.f};
    #pragma unroll
    for (int w = 0; w < 4; ++w) {
        s0 += *(const f32x4*)&red[w * 2304 + row * 36 + c0_];
        s1 += *(const f32x4*)&red[w * 2304 + row * 36 + c0_ + 4];
    }
    unsigned short hh[8], ll[8];
    #pragma unroll
    for (int j = 0; j < 4; ++j) {
        float ev = elu1(s0[j]);
        hh[j] = bfh(ev); ll[j] = bfh(ev - bf2f(hh[j]));
        float ev2 = elu1(s1[j]);
        hh[4 + j] = bfh(ev2); ll[4 + j] = bfh(ev2 - bf2f(hh[4 + j]));
    }
    size_t o = (size_t)(brow + row) * INTER + 32 + bn + c0_;
    *(short8*)&outH[o] = *(const short8*)hh;
    *(short8*)&outL[o] = *(const short8*)ll;
}

// ---------- small GEMM: weight-stationary, zero barriers in K loop ----------
// Block: 128 thr / 2 waves, tile 16 rows x NCOL cols (waves split cols).
// Whole B-slice [NCOL][K] hi/lo loaded to LDS once; A in registers.
template<int KS, int NCOL, int OUTM, int SOUT, int OFS>
__global__ __launch_bounds__(128, 2) void k_small(
    const unsigned short* __restrict__ Ah, const unsigned short* __restrict__ Al,
    const unsigned short* __restrict__ Bh, const unsigned short* __restrict__ Bl,
    const float* __restrict__ bias,
    float* __restrict__ outF, unsigned short* __restrict__ outH,
    unsigned short* __restrict__ outL)
{
    constexpr int K  = KS * 32;
    constexpr int NG = NCOL / 16;     // 16-col groups
    constexpr int NF = NCOL / 32;     // frags per wave
    constexpr int CT = 128 / NCOL;    // col tiles in grid
    __shared__ __align__(16) char smem[KS * NG * 2 * 1024];

    const int tid = threadIdx.x, wid = tid >> 6, l = tid & 63;
    const int brow = (blockIdx.x / CT) * 16;
    const int bn   = (blockIdx.x % CT) * NCOL;

    // A -> registers (MFMA frag layout: row = l&15, chunk = l>>4)
    const unsigned short* Arh = Ah + (size_t)(brow + (l & 15)) * K + (l >> 4) * 8;
    const unsigned short* Arl = Al + (size_t)(brow + (l & 15)) * K + (l >> 4) * 8;
    i32x4 ah_[KS], al_[KS];
    #pragma unroll
    for (int ks = 0; ks < KS; ++ks) {
        ah_[ks] = *(const i32x4*)(Arh + ks * 32);
        al_[ks] = *(const i32x4*)(Arl + ks * 32);
    }

    // stage whole B slice (each wave: half the (ks,g) pairs)
    const int swz = (((l & 3) ^ ((l >> 3) & 3)) << 3);
    const int rq  = l >> 2;
    #pragma unroll
    for (int p = 0; p < KS * NG; ++p) {
        if ((p & 1) != wid) continue;
        const int ks = p / NG, g = p % NG;
        const size_t so = (size_t)(bn + g * 16 + rq) * K + ks * 32 + swz;
        gload16(Bh + so, smem + p * 2048);
        gload16(Bl + so, smem + p * 2048 + 1024);
    }
    __syncthreads();   // full vmcnt drain covers A regs too

    const int rdo = ((l & 15) << 6) + (((l >> 4) ^ ((l >> 1) & 3)) << 4);
    f32x4 acc[NF];
    #pragma unroll
    for (int nf = 0; nf < NF; ++nf) {
        float bv = bias[bn + wid * (NCOL / 2) + nf * 16 + (l & 15)];
        acc[nf] = (f32x4){bv, bv, bv, bv};
    }
    #pragma unroll
    for (int ks = 0; ks < KS; ++ks)
        #pragma unroll
        for (int nf = 0; nf < NF; ++nf) {
            const char* bp = smem + (size_t)(ks * NG + wid * NF + nf) * 2048;
            short8 bh = *(const short8*)(bp + rdo);
            short8 bl = *(const short8*)(bp + 1024 + rdo);
            acc[nf] = __builtin_amdgcn_mfma_f32_16x16x32_bf16(as_s8(ah_[ks]), bh, acc[nf], 0, 0, 0);
            acc[nf] = __builtin_amdgcn_mfma_f32_16x16x32_bf16(as_s8(ah_[ks]), bl, acc[nf], 0, 0, 0);
            acc[nf] = __builtin_amdgcn_mfma_f32_16x16x32_bf16(as_s8(al_[ks]), bh, acc[nf], 0, 0, 0);
        }

    #pragma unroll
    for (int nf = 0; nf < NF; ++nf)
        #pragma unroll
        for (int r = 0; r < 4; ++r) {
            const int row = brow + ((l >> 4) << 2) + r;
            const int col = bn + wid * (NCOL / 2) + nf * 16 + (l & 15);
            size_t o = (size_t)row * SOUT + OFS + col;
            float v = acc[nf][r];
            if (OUTM == 0) {
                outF[o] = v;
            } else if (OUTM == 2) {
                outF[o] = elu1(v);
            } else {
                float ev = elu1(v);
                unsigned short h = bfh(ev);
                unsigned short lo = bfh(ev - bf2f(h));
                outH[o] = h; outL[o] = lo;
            }
        }
}

// ---------- gate output layer + softmax over 8 experts (one wave/row) ----------
__global__ __launch_bounds__(256) void k_gate_out(
    const float* __restrict__ G2, const float* __restrict__ g2w,
    const float* __restrict__ g2b, float* __restrict__ coeff)
{
    __shared__ float wt[NE][GH];
    int tid = threadIdx.x;
    for (int idx = tid; idx < GH * NE; idx += 256) {
        int k = idx >> 3, e = idx & 7;
        wt[e][k] = g2w[idx];
    }
    __syncthreads();
    int row  = (blockIdx.x * 256 + tid) >> 6;
    int lane = tid & 63;
    if (row >= B_) return;
    float a0 = G2[(size_t)row * GH + lane];
    float a1 = G2[(size_t)row * GH + 64 + lane];
    float p[NE];
    #pragma unroll
    for (int e = 0; e < NE; ++e)
        p[e] = a0 * wt[e][lane] + a1 * wt[e][lane + 64];
    #pragma unroll
    for (int o = 32; o; o >>= 1) {
        #pragma unroll
        for (int e = 0; e < NE; ++e) p[e] += __shfl_xor(p[e], o);
    }
    float mx = -1e30f;
    #pragma unroll
    for (int e = 0; e < NE; ++e) { p[e] += g2b[e]; mx = fmaxf(mx, p[e]); }
    float s = 0.0f;
    #pragma unroll
    for (int e = 0; e < NE; ++e) { p[e] = expf(p[e] - mx); s += p[e]; }
    float inv = 1.0f / s;
    if (lane == 0) {
        #pragma unroll
        for (int e = 0; e < NE; ++e) coeff[(size_t)row * NE + e] = p[e] * inv;
    }
}

// ---------- final mix: out[b,o] = sum_e cf[b,e] * P[b, e*16+o] ----------
__global__ __launch_bounds__(256) void k_mix(
    const float* __restrict__ P, const float* __restrict__ cf, float* __restrict__ out)
{
    int id = blockIdx.x * 256 + threadIdx.x;
    if (id >= B_ * ACTD) return;
    int b = id >> 4, o = id & 15;
    const float* pr = P + (size_t)b * 128 + o;
    const float* cr = cf + (size_t)b * 8;
    float s = 0.f;
    #pragma unroll
    for (int e = 0; e < 8; ++e) s += cr[e] * pr[e * 16];
    out[id] = s;
}

extern "C" void kernel_launch(void* const* d_in, const int* in_sizes, int n_in,
                              void* d_out, int out_size, void* d_ws, size_t ws_size,
                              hipStream_t stream)
{
    (void)in_sizes; (void)n_in; (void)out_size; (void)ws_size;
    const float* z   = (const float*)d_in[0];
    const float* c   = (const float*)d_in[1];
    const float* w0  = (const float*)d_in[2];
    const float* b0  = (const float*)d_in[3];
    const float* w1  = (const float*)d_in[4];
    const float* b1  = (const float*)d_in[5];
    const float* w2  = (const float*)d_in[6];
    const float* b2  = (const float*)d_in[7];
    const float* g0w = (const float*)d_in[8];
    const float* g0b = (const float*)d_in[9];
    const float* g1w = (const float*)d_in[10];
    const float* g1b = (const float*)d_in[11];
    const float* g2w = (const float*)d_in[12];
    const float* g2b = (const float*)d_in[13];
    const float* lng = (const float*)d_in[14];
    const float* lnb = (const float*)d_in[15];
    float* out = (float*)d_out;

    char* p = (char*)d_ws;
    auto alloc = [&](size_t n) { char* r = p; p += (n + 255) & ~(size_t)255; return r; };
    unsigned short* X0h = (unsigned short*)alloc((size_t)B_ * IN0 * 2);
    unsigned short* X0l = (unsigned short*)alloc((size_t)B_ * IN0 * 2);
    unsigned short* X1h = (unsigned short*)alloc((size_t)B_ * INTER * 2);
    unsigned short* X1l = (unsigned short*)alloc((size_t)B_ * INTER * 2);
    unsigned short* X2h = (unsigned short*)alloc((size_t)B_ * INTER * 2);
    unsigned short* X2l = (unsigned short*)alloc((size_t)B_ * INTER * 2);
    unsigned short* G1h = (unsigned short*)alloc((size_t)B_ * GH * 2);
    unsigned short* G1l = (unsigned short*)alloc((size_t)B_ * GH * 2);
    float* G2f = (float*)alloc((size_t)B_ * GH * 4);      // reused as P2 after gate_out
    float* cf  = (float*)alloc((size_t)B_ * NE * 4);
    unsigned short* T0h = (unsigned short*)alloc((size_t)NE * IN0 * HID * 2);
    unsigned short* T0l = (unsigned short*)alloc((size_t)NE * IN0 * HID * 2);
    unsigned short* T1h = (unsigned short*)alloc((size_t)NE * INTER * HID * 2);
    unsigned short* T1l = (unsigned short*)alloc((size_t)NE * INTER * HID * 2);
    unsigned short* T2h = (unsigned short*)alloc((size_t)NE * INTER * ACTD * 2);
    unsigned short* T2l = (unsigned short*)alloc((size_t)NE * INTER * ACTD * 2);
    unsigned short* G0Th = (unsigned short*)alloc((size_t)IN0 * GH * 2);
    unsigned short* G0Tl = (unsigned short*)alloc((size_t)IN0 * GH * 2);
    unsigned short* G1Th = (unsigned short*)alloc((size_t)GH * GH * 2);
    unsigned short* G1Tl = (unsigned short*)alloc((size_t)GH * GH * 2);
    float* P2 = G2f;

    k_prep<<<dim3(3872), dim3(256), 0, stream>>>(w0, w1, w2, g0w, g1w,
        T0h, T0l, T1h, T1l, T2h, T2l, G0Th, G0Tl, G1Th, G1Tl);
    k_ln_concat2<<<dim3(B_ / 4), dim3(256), 0, stream>>>(z, c, lng, lnb,
        X0h, X0l, X1h, X1l, X2h, X2l);

    // gate MLP: X0 -> G1 (bf16 hi/lo) -> G2f (fp32+elu) -> coeff
    k_small<5, 64, 1, 128, 0><<<dim3(1024), dim3(128), 0, stream>>>(
        X0h, X0l, G0Th, G0Tl, g0b, nullptr, G1h, G1l);
    k_small<4, 64, 2, 128, 0><<<dim3(1024), dim3(128), 0, stream>>>(
        G1h, G1l, G1Th, G1Tl, g1b, G2f, nullptr, nullptr);
    k_gate_out<<<dim3(B_ / 4), dim3(256), 0, stream>>>(G2f, g2w, g2b, cf);

    // expert layers: expert-parallel waves, cross-wave cf reduction
    k_moe_epar<5><<<dim3(1024), dim3(256), 0, stream>>>(
        X0h, X0l, T0h, T0l, b0, cf, X1h, X1l);
    k_moe_epar<9><<<dim3(1024), dim3(256), 0, stream>>>(
        X1h, X1l, T1h, T1l, b1, cf, X2h, X2l);
    // final layer as plain GEMM over N = E*16 = 128, then coeff-mix
    k_small<9, 32, 0, 128, 0><<<dim3(2048), dim3(128), 0, stream>>>(
        X2h, X2l, T2h, T2l, b2, P2, nullptr, nullptr);
    k_mix<<<dim3(B_ * ACTD / 256), dim3(256), 0, stream>>>(P2, cf, out);
}

// Round 6
// 106.001 us; speedup vs baseline: 1.5919x; 1.1022x over previous
//
#include <hip/hip_runtime.h>
#include <hip/hip_bf16.h>
#include <math.h>

#define B_     8192
#define LATENT 32
#define CIN    128
#define HID    256
#define ACTD   16
#define NE     8
#define GH     128
#define IN0    160   // LATENT + CIN
#define INTER  288   // HID + LATENT

typedef __attribute__((ext_vector_type(8))) short short8;
typedef __attribute__((ext_vector_type(4))) float f32x4;
typedef __attribute__((ext_vector_type(4))) int   i32x4;

__device__ __forceinline__ float elu1(float x) { return x > 0.0f ? x : expm1f(x); }

__device__ __forceinline__ unsigned short bfh(float v) {
    __hip_bfloat16 b = __float2bfloat16(v);
    return *reinterpret_cast<unsigned short*>(&b);
}
__device__ __forceinline__ float bf2f(unsigned short u) {
    __hip_bfloat16 b;
    *reinterpret_cast<unsigned short*>(&b) = u;
    return __bfloat162float(b);
}
__device__ __forceinline__ void gload16(const unsigned short* g, const char* lds) {
    __builtin_amdgcn_global_load_lds((const __attribute__((address_space(1))) void*)g,
                                     (__attribute__((address_space(3))) void*)lds, 16, 0, 0);
}
__device__ __forceinline__ short8 as_s8(i32x4 v) {
    union U { i32x4 a; short8 b; } u; u.a = v; return u.b;
}

// ---------- prep (gather form): coalesced short8 writes, strided reads ----------
// Each thread: 8 consecutive DST elements -> 1x short8 store to H and L.
__global__ __launch_bounds__(256) void k_prep_g(
    const float* __restrict__ w0, const float* __restrict__ w1, const float* __restrict__ w2,
    const float* __restrict__ g0w, const float* __restrict__ g1w,
    unsigned short* __restrict__ T0h, unsigned short* __restrict__ T0l,
    unsigned short* __restrict__ T1h, unsigned short* __restrict__ T1l,
    unsigned short* __restrict__ T2h, unsigned short* __restrict__ T2l,
    unsigned short* __restrict__ G0h, unsigned short* __restrict__ G0l,
    unsigned short* __restrict__ G1h, unsigned short* __restrict__ G1l)
{
    int g = blockIdx.x * 256 + threadIdx.x;
    const float* src; int stride; size_t dst; unsigned short *H, *L;
    if (g < 40960) {                       // T0: [8][160][256] -> [8*256][160]
        int e = g / 5120, r = g % 5120, o = r / 20, i0 = (r % 20) * 8;
        src = w0 + ((size_t)e * 160 + i0) * 256 + o; stride = 256;
        dst = ((size_t)e * 256 + o) * 160 + i0; H = T0h; L = T0l;
    } else if (g < 114688) {               // T1: [8][288][256] -> [8*256][288]
        int t = g - 40960;
        int e = t / 9216, r = t % 9216, o = r / 36, i0 = (r % 36) * 8;
        src = w1 + ((size_t)e * 288 + i0) * 256 + o; stride = 256;
        dst = ((size_t)e * 256 + o) * 288 + i0; H = T1h; L = T1l;
    } else if (g < 119296) {               // T2: [8][288][16] -> [8*16][288]
        int t = g - 114688;
        int e = t / 576, r = t % 576, o = r / 36, i0 = (r % 36) * 8;
        src = w2 + ((size_t)e * 288 + i0) * 16 + o; stride = 16;
        dst = ((size_t)e * 16 + o) * 288 + i0; H = T2h; L = T2l;
    } else if (g < 121856) {               // G0: [160][128] -> [128][160]
        int t = g - 119296;
        int o = t / 20, i0 = (t % 20) * 8;
        src = g0w + (size_t)i0 * 128 + o; stride = 128;
        dst = (size_t)o * 160 + i0; H = G0h; L = G0l;
    } else if (g < 123904) {               // G1: [128][128] -> [128][128]
        int t = g - 121856;
        int o = t / 16, i0 = (t % 16) * 8;
        src = g1w + (size_t)i0 * 128 + o; stride = 128;
        dst = (size_t)o * 128 + i0; H = G1h; L = G1l;
    } else return;
    unsigned short hh[8], ll[8];
    #pragma unroll
    for (int j = 0; j < 8; ++j) {
        float v = src[(size_t)j * stride];
        hh[j] = bfh(v);
        ll[j] = bfh(v - bf2f(hh[j]));
    }
    *(short8*)&H[dst] = *(const short8*)hh;
    *(short8*)&L[dst] = *(const short8*)ll;
}

// ---------- LayerNorm + concat, split to hi/lo; also seed z into X1/X2 ----------
__global__ __launch_bounds__(256) void k_ln_concat2(
    const float* __restrict__ z, const float* __restrict__ c,
    const float* __restrict__ g, const float* __restrict__ bt,
    unsigned short* __restrict__ X0h, unsigned short* __restrict__ X0l,
    unsigned short* __restrict__ X1h, unsigned short* __restrict__ X1l,
    unsigned short* __restrict__ X2h, unsigned short* __restrict__ X2l)
{
    int gid = blockIdx.x * 256 + threadIdx.x;
    int row = gid >> 6;
    int l = threadIdx.x & 63;
    if (row >= B_) return;
    const float* cr = c + (size_t)row * CIN;
    float v0 = cr[l], v1 = cr[l + 64];
    float s = v0 + v1;
    #pragma unroll
    for (int o = 32; o; o >>= 1) s += __shfl_xor(s, o);
    float mean = s * (1.0f / 128.0f);
    float d0 = v0 - mean, d1 = v1 - mean;
    float q = d0 * d0 + d1 * d1;
    #pragma unroll
    for (int o = 32; o; o >>= 1) q += __shfl_xor(q, o);
    float rstd = rsqrtf(q * (1.0f / 128.0f) + 1e-5f);
    float y0 = d0 * rstd * g[l] + bt[l];
    float y1 = d1 * rstd * g[l + 64] + bt[l + 64];
    size_t r0 = (size_t)row * IN0;
    unsigned short h0 = bfh(y0), lo0 = bfh(y0 - bf2f(h0));
    unsigned short h1 = bfh(y1), lo1 = bfh(y1 - bf2f(h1));
    X0h[r0 + 32 + l] = h0; X0l[r0 + 32 + l] = lo0;
    X0h[r0 + 96 + l] = h1; X0l[r0 + 96 + l] = lo1;
    if (l < LATENT) {
        float zv = z[(size_t)row * LATENT + l];
        unsigned short zh = bfh(zv), zl = bfh(zv - bf2f(zh));
        X0h[r0 + l] = zh; X0l[r0 + l] = zl;
        size_t r1 = (size_t)row * INTER;
        X1h[r1 + l] = zh; X1l[r1 + l] = zl;
        X2h[r1 + l] = zh; X2l[r1 + l] = zl;
    }
}

// ---------- MoE layer: expert-parallel waves, big MFMA clusters ----------
template<int KS>
__global__ __launch_bounds__(256, 2) void k_moe_epar(
    const unsigned short* __restrict__ Ah, const unsigned short* __restrict__ Al,
    const unsigned short* __restrict__ Bh, const unsigned short* __restrict__ Bl,
    const float* __restrict__ bias,   // [8][256]
    const float* __restrict__ coeff,  // [B][8]
    unsigned short* __restrict__ outH, unsigned short* __restrict__ outL)
{
    constexpr int K = KS * 32;
    __shared__ __align__(16) char smem[81920];   // 2 bufs x (A 8KB + B 32KB)

    const int tid = threadIdx.x, wid = tid >> 6, l = tid & 63;
    const int brow = (blockIdx.x >> 3) * 64;
    const int bn   = (blockIdx.x & 7) * 32;      // each XCD -> one col slice

    const int swz = (((l & 3) ^ ((l >> 3) & 3)) << 3);
    const int rq  = l >> 2;
    const unsigned short* sA[2];
    sA[0] = Ah + (size_t)(brow + wid * 16 + rq) * K + swz;
    sA[1] = Al + (size_t)(brow + wid * 16 + rq) * K + swz;
    const unsigned short* sB2[2][2];
    #pragma unroll
    for (int e2 = 0; e2 < 2; ++e2) {
        sB2[e2][0] = Bh + (size_t)((2 * wid + e2) * HID + bn + rq) * K + swz;
        sB2[e2][1] = Bl + (size_t)((2 * wid + e2) * HID + bn + rq) * K + swz;
    }

    auto stage = [&](int bi, int k0) {   // 10 gload16 per lane
        char* buf = smem + bi * 40960;
        #pragma unroll
        for (int h = 0; h < 2; ++h)
            gload16(sA[h] + k0, buf + h * 4096 + wid * 1024);
        #pragma unroll
        for (int e2 = 0; e2 < 2; ++e2)
            #pragma unroll
            for (int h = 0; h < 2; ++h)
                #pragma unroll
                for (int g = 0; g < 2; ++g)
                    gload16(sB2[e2][h] + g * 16 * K + k0,
                            buf + 8192 + (2 * wid + e2) * 4096 + h * 2048 + g * 1024);
    };

    const int rdo = ((l & 15) << 6) + (((l >> 4) ^ ((l >> 1) & 3)) << 4);
    f32x4 acc[2][4][2];
    #pragma unroll
    for (int e2 = 0; e2 < 2; ++e2)
        #pragma unroll
        for (int mf = 0; mf < 4; ++mf)
            #pragma unroll
            for (int nf = 0; nf < 2; ++nf) acc[e2][mf][nf] = (f32x4){0.f, 0.f, 0.f, 0.f};

    stage(0, 0);
    __syncthreads();

    for (int t = 0; t < KS; ++t) {
        if (t + 1 < KS) {
            stage((t + 1) & 1, (t + 1) * 32);
            asm volatile("s_waitcnt vmcnt(10)" ::: "memory");
        } else {
            asm volatile("s_waitcnt vmcnt(0)" ::: "memory");
        }
        __builtin_amdgcn_s_barrier();
        __builtin_amdgcn_sched_barrier(0);

        const char* buf = smem + (t & 1) * 40960;
        short8 afh[4], afl[4];
        #pragma unroll
        for (int mf = 0; mf < 4; ++mf) {
            afh[mf] = *(const short8*)(buf + mf * 1024 + rdo);
            afl[mf] = *(const short8*)(buf + 4096 + mf * 1024 + rdo);
        }
        __builtin_amdgcn_s_setprio(1);
        #pragma unroll
        for (int e2 = 0; e2 < 2; ++e2) {
            const char* be = buf + 8192 + (2 * wid + e2) * 4096;
            short8 bh0 = *(const short8*)(be + rdo);
            short8 bh1 = *(const short8*)(be + 1024 + rdo);
            short8 bl0 = *(const short8*)(be + 2048 + rdo);
            short8 bl1 = *(const short8*)(be + 3072 + rdo);
            #pragma unroll
            for (int mf = 0; mf < 4; ++mf) {
                acc[e2][mf][0] = __builtin_amdgcn_mfma_f32_16x16x32_bf16(afh[mf], bh0, acc[e2][mf][0], 0, 0, 0);
                acc[e2][mf][0] = __builtin_amdgcn_mfma_f32_16x16x32_bf16(afh[mf], bl0, acc[e2][mf][0], 0, 0, 0);
                acc[e2][mf][0] = __builtin_amdgcn_mfma_f32_16x16x32_bf16(afl[mf], bh0, acc[e2][mf][0], 0, 0, 0);
                acc[e2][mf][1] = __builtin_amdgcn_mfma_f32_16x16x32_bf16(afh[mf], bh1, acc[e2][mf][1], 0, 0, 0);
                acc[e2][mf][1] = __builtin_amdgcn_mfma_f32_16x16x32_bf16(afh[mf], bl1, acc[e2][mf][1], 0, 0, 0);
                acc[e2][mf][1] = __builtin_amdgcn_mfma_f32_16x16x32_bf16(afl[mf], bh1, acc[e2][mf][1], 0, 0, 0);
            }
        }
        __builtin_amdgcn_s_setprio(0);
        asm volatile("s_waitcnt lgkmcnt(0)" ::: "memory");
        __builtin_amdgcn_sched_barrier(0);
        __builtin_amdgcn_s_barrier();
    }

    // ---- epilogue: cf table -> LDS, scale partials, cross-wave reduce ----
    float* cfl = (float*)(smem + 73728);             // [64][8]
    if (tid < 128) {
        f32x4 v = *(const f32x4*)&coeff[(size_t)(brow + (tid >> 1)) * 8 + (tid & 1) * 4];
        *(f32x4*)&cfl[tid * 4] = v;
    }
    __syncthreads();

    const int e0 = 2 * wid, e1 = 2 * wid + 1;
    float bv0[2], bv1[2];
    #pragma unroll
    for (int nf = 0; nf < 2; ++nf) {
        bv0[nf] = bias[e0 * HID + bn + nf * 16 + (l & 15)];
        bv1[nf] = bias[e1 * HID + bn + nf * 16 + (l & 15)];
    }
    float* red = (float*)smem;                        // [4][64][36]
    #pragma unroll
    for (int mf = 0; mf < 4; ++mf) {
        const int rb = mf * 16 + ((l >> 4) << 2);
        #pragma unroll
        for (int r = 0; r < 4; ++r) {
            float c0 = cfl[(rb + r) * 8 + e0];
            float c1 = cfl[(rb + r) * 8 + e1];
            #pragma unroll
            for (int nf = 0; nf < 2; ++nf) {
                float s = (acc[0][mf][nf][r] + bv0[nf]) * c0
                        + (acc[1][mf][nf][r] + bv1[nf]) * c1;
                red[wid * 2304 + (rb + r) * 36 + nf * 16 + (l & 15)] = s;
            }
        }
    }
    __syncthreads();

    const int row = tid >> 2, c0_ = (tid & 3) * 8;
    f32x4 s0 = {0.f, 0.f, 0.f, 0.f}, s1 = {0.f, 0.f, 0.f, 0.f};
    #pragma unroll
    for (int w = 0; w < 4; ++w) {
        s0 += *(const f32x4*)&red[w * 2304 + row * 36 + c0_];
        s1 += *(const f32x4*)&red[w * 2304 + row * 36 + c0_ + 4];
    }
    unsigned short hh[8], ll[8];
    #pragma unroll
    for (int j = 0; j < 4; ++j) {
        float ev = elu1(s0[j]);
        hh[j] = bfh(ev); ll[j] = bfh(ev - bf2f(hh[j]));
        float ev2 = elu1(s1[j]);
        hh[4 + j] = bfh(ev2); ll[4 + j] = bfh(ev2 - bf2f(hh[4 + j]));
    }
    size_t o = (size_t)(brow + row) * INTER + 32 + bn + c0_;
    *(short8*)&outH[o] = *(const short8*)hh;
    *(short8*)&outL[o] = *(const short8*)ll;
}

// ---------- small GEMM: 64-row / 4-wave, weight-stationary, no K-loop barriers ----------
// Block: 256 thr / 4 waves; wave owns 16 rows x NCOL cols. Whole B slice in LDS.
template<int KS, int NCOL, int OUTM, int SOUT, int OFS>
__global__ __launch_bounds__(256, 2) void k_small64(
    const unsigned short* __restrict__ Ah, const unsigned short* __restrict__ Al,
    const unsigned short* __restrict__ Bh, const unsigned short* __restrict__ Bl,
    const float* __restrict__ bias,
    float* __restrict__ outF, unsigned short* __restrict__ outH,
    unsigned short* __restrict__ outL)
{
    constexpr int K  = KS * 32;
    constexpr int NG = NCOL / 16;     // 16-col groups
    constexpr int CT = 128 / NCOL;    // col tiles in grid
    __shared__ __align__(16) char smem[KS * NG * 2048];

    const int tid = threadIdx.x, wid = tid >> 6, l = tid & 63;
    const int brow = (blockIdx.x / CT) * 64 + wid * 16;
    const int bn   = (blockIdx.x % CT) * NCOL;

    // A -> registers (MFMA frag layout: row = l&15, chunk = l>>4)
    const unsigned short* Arh = Ah + (size_t)(brow + (l & 15)) * K + (l >> 4) * 8;
    const unsigned short* Arl = Al + (size_t)(brow + (l & 15)) * K + (l >> 4) * 8;
    i32x4 ah_[KS], al_[KS];
    #pragma unroll
    for (int ks = 0; ks < KS; ++ks) {
        ah_[ks] = *(const i32x4*)(Arh + ks * 32);
        al_[ks] = *(const i32x4*)(Arl + ks * 32);
    }

    // stage whole B slice; waves split the (ks,g) units
    const int swz = (((l & 3) ^ ((l >> 3) & 3)) << 3);
    const int rq  = l >> 2;
    #pragma unroll
    for (int p = 0; p < KS * NG; ++p) {
        if ((p & 3) != wid) continue;
        const int ks = p / NG, g = p % NG;
        const size_t so = (size_t)(bn + g * 16 + rq) * K + ks * 32 + swz;
        gload16(Bh + so, smem + p * 2048);
        gload16(Bl + so, smem + p * 2048 + 1024);
    }
    __syncthreads();   // full drain

    const int rdo = ((l & 15) << 6) + (((l >> 4) ^ ((l >> 1) & 3)) << 4);
    f32x4 acc[NG];
    #pragma unroll
    for (int nf = 0; nf < NG; ++nf) {
        float bv = bias[bn + nf * 16 + (l & 15)];
        acc[nf] = (f32x4){bv, bv, bv, bv};
    }
    #pragma unroll
    for (int ks = 0; ks < KS; ++ks)
        #pragma unroll
        for (int nf = 0; nf < NG; ++nf) {
            const char* bp = smem + (size_t)(ks * NG + nf) * 2048;
            short8 bh = *(const short8*)(bp + rdo);
            short8 bl = *(const short8*)(bp + 1024 + rdo);
            acc[nf] = __builtin_amdgcn_mfma_f32_16x16x32_bf16(as_s8(ah_[ks]), bh, acc[nf], 0, 0, 0);
            acc[nf] = __builtin_amdgcn_mfma_f32_16x16x32_bf16(as_s8(ah_[ks]), bl, acc[nf], 0, 0, 0);
            acc[nf] = __builtin_amdgcn_mfma_f32_16x16x32_bf16(as_s8(al_[ks]), bh, acc[nf], 0, 0, 0);
        }

    #pragma unroll
    for (int nf = 0; nf < NG; ++nf)
        #pragma unroll
        for (int r = 0; r < 4; ++r) {
            const int row = brow + ((l >> 4) << 2) + r;
            const int col = bn + nf * 16 + (l & 15);
            size_t o = (size_t)row * SOUT + OFS + col;
            float v = acc[nf][r];
            if (OUTM == 0) {
                outF[o] = v;
            } else if (OUTM == 2) {
                outF[o] = elu1(v);
            } else {
                float ev = elu1(v);
                unsigned short h = bfh(ev);
                unsigned short lo = bfh(ev - bf2f(h));
                outH[o] = h; outL[o] = lo;
            }
        }
}

// ---------- gate output layer + softmax over 8 experts (one wave/row) ----------
__global__ __launch_bounds__(256) void k_gate_out(
    const float* __restrict__ G2, const float* __restrict__ g2w,
    const float* __restrict__ g2b, float* __restrict__ coeff)
{
    __shared__ float wt[NE][GH];
    int tid = threadIdx.x;
    for (int idx = tid; idx < GH * NE; idx += 256) {
        int k = idx >> 3, e = idx & 7;
        wt[e][k] = g2w[idx];
    }
    __syncthreads();
    int row  = (blockIdx.x * 256 + tid) >> 6;
    int lane = tid & 63;
    if (row >= B_) return;
    float a0 = G2[(size_t)row * GH + lane];
    float a1 = G2[(size_t)row * GH + 64 + lane];
    float p[NE];
    #pragma unroll
    for (int e = 0; e < NE; ++e)
        p[e] = a0 * wt[e][lane] + a1 * wt[e][lane + 64];
    #pragma unroll
    for (int o = 32; o; o >>= 1) {
        #pragma unroll
        for (int e = 0; e < NE; ++e) p[e] += __shfl_xor(p[e], o);
    }
    float mx = -1e30f;
    #pragma unroll
    for (int e = 0; e < NE; ++e) { p[e] += g2b[e]; mx = fmaxf(mx, p[e]); }
    float s = 0.0f;
    #pragma unroll
    for (int e = 0; e < NE; ++e) { p[e] = expf(p[e] - mx); s += p[e]; }
    float inv = 1.0f / s;
    if (lane == 0) {
        #pragma unroll
        for (int e = 0; e < NE; ++e) coeff[(size_t)row * NE + e] = p[e] * inv;
    }
}

// ---------- final mix: out[b,o] = sum_e cf[b,e] * P[b, e*16+o] ----------
__global__ __launch_bounds__(256) void k_mix(
    const float* __restrict__ P, const float* __restrict__ cf, float* __restrict__ out)
{
    int id = blockIdx.x * 256 + threadIdx.x;
    if (id >= B_ * ACTD) return;
    int b = id >> 4, o = id & 15;
    const float* pr = P + (size_t)b * 128 + o;
    const float* cr = cf + (size_t)b * 8;
    float s = 0.f;
    #pragma unroll
    for (int e = 0; e < 8; ++e) s += cr[e] * pr[e * 16];
    out[id] = s;
}

extern "C" void kernel_launch(void* const* d_in, const int* in_sizes, int n_in,
                              void* d_out, int out_size, void* d_ws, size_t ws_size,
                              hipStream_t stream)
{
    (void)in_sizes; (void)n_in; (void)out_size; (void)ws_size;
    const float* z   = (const float*)d_in[0];
    const float* c   = (const float*)d_in[1];
    const float* w0  = (const float*)d_in[2];
    const float* b0  = (const float*)d_in[3];
    const float* w1  = (const float*)d_in[4];
    const float* b1  = (const float*)d_in[5];
    const float* w2  = (const float*)d_in[6];
    const float* b2  = (const float*)d_in[7];
    const float* g0w = (const float*)d_in[8];
    const float* g0b = (const float*)d_in[9];
    const float* g1w = (const float*)d_in[10];
    const float* g1b = (const float*)d_in[11];
    const float* g2w = (const float*)d_in[12];
    const float* g2b = (const float*)d_in[13];
    const float* lng = (const float*)d_in[14];
    const float* lnb = (const float*)d_in[15];
    float* out = (float*)d_out;

    char* p = (char*)d_ws;
    auto alloc = [&](size_t n) { char* r = p; p += (n + 255) & ~(size_t)255; return r; };
    unsigned short* X0h = (unsigned short*)alloc((size_t)B_ * IN0 * 2);
    unsigned short* X0l = (unsigned short*)alloc((size_t)B_ * IN0 * 2);
    unsigned short* X1h = (unsigned short*)alloc((size_t)B_ * INTER * 2);
    unsigned short* X1l = (unsigned short*)alloc((size_t)B_ * INTER * 2);
    unsigned short* X2h = (unsigned short*)alloc((size_t)B_ * INTER * 2);
    unsigned short* X2l = (unsigned short*)alloc((size_t)B_ * INTER * 2);
    unsigned short* G1h = (unsigned short*)alloc((size_t)B_ * GH * 2);
    unsigned short* G1l = (unsigned short*)alloc((size_t)B_ * GH * 2);
    float* G2f = (float*)alloc((size_t)B_ * GH * 4);      // reused as P2 after gate_out
    float* cf  = (float*)alloc((size_t)B_ * NE * 4);
    unsigned short* T0h = (unsigned short*)alloc((size_t)NE * IN0 * HID * 2);
    unsigned short* T0l = (unsigned short*)alloc((size_t)NE * IN0 * HID * 2);
    unsigned short* T1h = (unsigned short*)alloc((size_t)NE * INTER * HID * 2);
    unsigned short* T1l = (unsigned short*)alloc((size_t)NE * INTER * HID * 2);
    unsigned short* T2h = (unsigned short*)alloc((size_t)NE * INTER * ACTD * 2);
    unsigned short* T2l = (unsigned short*)alloc((size_t)NE * INTER * ACTD * 2);
    unsigned short* G0Th = (unsigned short*)alloc((size_t)IN0 * GH * 2);
    unsigned short* G0Tl = (unsigned short*)alloc((size_t)IN0 * GH * 2);
    unsigned short* G1Th = (unsigned short*)alloc((size_t)GH * GH * 2);
    unsigned short* G1Tl = (unsigned short*)alloc((size_t)GH * GH * 2);
    float* P2 = G2f;

    k_prep_g<<<dim3(484), dim3(256), 0, stream>>>(w0, w1, w2, g0w, g1w,
        T0h, T0l, T1h, T1l, T2h, T2l, G0Th, G0Tl, G1Th, G1Tl);
    k_ln_concat2<<<dim3(B_ / 4), dim3(256), 0, stream>>>(z, c, lng, lnb,
        X0h, X0l, X1h, X1l, X2h, X2l);

    // gate MLP: X0 -> G1 (bf16 hi/lo) -> G2f (fp32+elu) -> coeff
    k_small64<5, 64, 1, 128, 0><<<dim3(256), dim3(256), 0, stream>>>(
        X0h, X0l, G0Th, G0Tl, g0b, nullptr, G1h, G1l);
    k_small64<4, 64, 2, 128, 0><<<dim3(256), dim3(256), 0, stream>>>(
        G1h, G1l, G1Th, G1Tl, g1b, G2f, nullptr, nullptr);
    k_gate_out<<<dim3(B_ / 4), dim3(256), 0, stream>>>(G2f, g2w, g2b, cf);

    // expert layers: expert-parallel waves, cross-wave cf reduction
    k_moe_epar<5><<<dim3(1024), dim3(256), 0, stream>>>(
        X0h, X0l, T0h, T0l, b0, cf, X1h, X1l);
    k_moe_epar<9><<<dim3(1024), dim3(256), 0, stream>>>(
        X1h, X1l, T1h, T1l, b1, cf, X2h, X2l);
    // final layer as plain GEMM over N = E*16 = 128, then coeff-mix
    k_small64<9, 32, 0, 128, 0><<<dim3(512), dim3(256), 0, stream>>>(
        X2h, X2l, T2h, T2l, b2, P2, nullptr, nullptr);
    k_mix<<<dim3(B_ * ACTD / 256), dim3(256), 0, stream>>>(P2, cf, out);
}